// Round 17
// baseline (17.497 us; speedup 1.0000x reference)
//
#include <hip/hip_runtime.h>
#include <hip/hip_bf16.h>

// CEKT: y_t = sigmoid([h_t|e_t|x] @ Wp + bp)
//   h_t = (1-g)*prev_h + g*tanh(comb @ Wh + bh),  g = sigmoid(comb @ Wq + bq)
//   comb = [e_t | r_t | prev_h];  GAT branch is dead code w.r.t. y_t.
//
// Round-17: ROLE-split waves (vs r16's k-split). 256 blocks x 1024 thr.
//   waves 0-7  (G1): full-K GEMM1 for col-tile ct -> complete sums in-wave ->
//                    epilogue with NO reduction; h_t direct to A2 frag slots.
//   waves 8-15 (G2): all 12 Wp frags loaded up front; 8 static ksteps
//                    (s=4..11) run CONCURRENTLY with G1+epilogue; after
//                    barrier 2 only 4 h-ksteps + stores.
// 2 barriers, zero partial-sum LDS traffic (p1g/p1c/p2y deleted, -24 KB).
// Pure bf16 A+W (absmax pinned at 2^-8 across all numeric variants).
// W gathered from fp32 via dword loads + RNE cvt (d16 trap avoided).

typedef short s16x8 __attribute__((ext_vector_type(8)));
typedef float f32x4 __attribute__((ext_vector_type(4)));

constexpr int NKQ = 10;  // K1=320 -> 10 ksteps of 32
constexpr int NKP = 12;  // K2=384 -> 12 ksteps of 32

__device__ __forceinline__ ushort bf16_rne(float f) {
    union { float f; uint u; } a; a.f = f;
    return (ushort)((a.u + 0x7FFFu + ((a.u >> 16) & 1u)) >> 16);
}
__device__ __forceinline__ float fsigmoid(float z) {
    return 1.0f / (1.0f + __expf(-z));
}
__device__ __forceinline__ float ftanh(float z) {
    const float a = fabsf(z);
    const float t = __expf(-2.0f * a);
    const float r = (1.0f - t) / (1.0f + t);
    return copysignf(r, z);
}

// Gather one B-fragment (kstep s) from fp32 W, convert to bf16 in registers.
// Elem j: W[s*32 + krow + j][colW] -> 8 dword loads, stride 512B, imm offsets.
__device__ __forceinline__ s16x8 ldfrag(const float* __restrict__ W,
                                        int s, int krow, int colW) {
    const float* p = W + (s * 32 + krow) * 128 + colW;
    union { ushort u[8]; s16x8 v; } r;
#pragma unroll
    for (int j = 0; j < 8; ++j)
        r.u[j] = bf16_rne(p[j * 128]);
    return r.v;
}

__global__ __launch_bounds__(1024, 1) void cekt_fused(
    const float* __restrict__ x,
    const float* __restrict__ e_t,
    const float* __restrict__ r_t,
    const float* __restrict__ prev_h,
    const float* __restrict__ Wq,
    const float* __restrict__ Wh,
    const float* __restrict__ Wp,
    const float* __restrict__ bq,
    const float* __restrict__ bh,
    const float* __restrict__ bp,
    float* __restrict__ out)
{
    __shared__ alignas(16) ushort A1h[NKQ * 64 * 8];
    __shared__ alignas(16) ushort A2h[NKP * 64 * 8];

    const int t = threadIdx.x;
    const int row0 = blockIdx.x * 16;
    const int w = t >> 6, lane = t & 63;
    const int ct = w & 7, role = w >> 3;     // role 0 = G1, 1 = G2
    const int krow = (lane >> 4) * 8;
    const int colW = ct * 16 + (lane & 15);
    const int colL = lane & 15, rg = lane >> 4;
    const int col = ct * 16 + colL;

    // ---- per-role front-loaded global work ----
    s16x8 hq[5], hc[5];      // G1: phase-1 frags s=0..4
    s16x8 pH[8], rH[4];      // G2: all 12 Wp frags
    float ph4[4];            // G1: prev_h for the epilogue
    if (!role) {
#pragma unroll
        for (int si = 0; si < 5; ++si) {
            hq[si] = ldfrag(Wq, si, krow, colW);
            hc[si] = ldfrag(Wh, si, krow, colW);
        }
#pragma unroll
        for (int i2 = 0; i2 < 4; ++i2)
            ph4[i2] = prev_h[(row0 + rg * 4 + i2) * 128 + col];
    } else {
#pragma unroll
        for (int si = 0; si < 8; ++si)
            pH[si] = ldfrag(Wp, 4 + si, krow, colW);
#pragma unroll
        for (int si = 0; si < 4; ++si)
            rH[si] = ldfrag(Wp, si, krow, colW);
    }

    // ---- stage A1 (comb1), bf16, coalesced float4 per row ----
    for (int i = t; i < 1280; i += 1024) {
        const int row = i / 80, kq4 = i - row * 80;
        const int k0 = kq4 * 4;
        float4 v;
        if (k0 < 128)      v = *(const float4*)&e_t[(row0 + row) * 128 + k0];
        else if (k0 < 192) v = *(const float4*)&r_t[(row0 + row) * 64 + (k0 - 128)];
        else               v = *(const float4*)&prev_h[(row0 + row) * 128 + (k0 - 192)];
        const int s = k0 >> 5, q = (k0 >> 3) & 3, j0 = k0 & 7;
        const int base = (s * 64 + q * 16 + row) * 8 + j0;
        ushort hi4[4];
        hi4[0] = bf16_rne(v.x); hi4[1] = bf16_rne(v.y);
        hi4[2] = bf16_rne(v.z); hi4[3] = bf16_rne(v.w);
        *(uint2*)&A1h[base] = *(const uint2*)hi4;
    }
    // ---- stage A2 static part (s=4..11: e_t | x), bf16 ----
    {
        const int row = t >> 6, kr = t & 63;
        const int k0 = 128 + kr * 4;            // 128..380
        const float4 v = (k0 < 256)
            ? *(const float4*)&e_t[(row0 + row) * 128 + (k0 - 128)]
            : *(const float4*)&x[(row0 + row) * 128 + (k0 - 256)];
        const int s = k0 >> 5, q = (k0 >> 3) & 3, j0 = k0 & 7;
        const int base = (s * 64 + q * 16 + row) * 8 + j0;
        ushort hi4[4];
        hi4[0] = bf16_rne(v.x); hi4[1] = bf16_rne(v.y);
        hi4[2] = bf16_rne(v.z); hi4[3] = bf16_rne(v.w);
        *(uint2*)&A2h[base] = *(const uint2*)hi4;
    }
    __syncthreads();                                        // barrier 1

    f32x4 yacc = {0, 0, 0, 0};
    if (!role) {
        // ---- G1: issue remaining frags (s=5..9), then full-K GEMM1 ----
        s16x8 hq2[5], hc2[5];
#pragma unroll
        for (int si = 0; si < 5; ++si) {
            hq2[si] = ldfrag(Wq, 5 + si, krow, colW);
            hc2[si] = ldfrag(Wh, 5 + si, krow, colW);
        }
        f32x4 gacc = {0, 0, 0, 0}, cacc = {0, 0, 0, 0};
#pragma unroll
        for (int si = 0; si < 5; ++si) {
            const s16x8 aH = *(const s16x8*)&A1h[(si * 64 + lane) * 8];
            gacc = __builtin_amdgcn_mfma_f32_16x16x32_bf16(aH, hq[si], gacc, 0, 0, 0);
            cacc = __builtin_amdgcn_mfma_f32_16x16x32_bf16(aH, hc[si], cacc, 0, 0, 0);
        }
#pragma unroll
        for (int si = 0; si < 5; ++si) {
            const s16x8 aH = *(const s16x8*)&A1h[((5 + si) * 64 + lane) * 8];
            gacc = __builtin_amdgcn_mfma_f32_16x16x32_bf16(aH, hq2[si], gacc, 0, 0, 0);
            cacc = __builtin_amdgcn_mfma_f32_16x16x32_bf16(aH, hc2[si], cacc, 0, 0, 0);
        }
        // ---- epilogue (no reduction): h_t -> A2 frag slots, ksteps 0..3 ----
        const float bqv = bq[col], bhv = bh[col];
        const int s_h = col >> 5, q_h = (col >> 3) & 3, j_h = col & 7;
#pragma unroll
        for (int i2 = 0; i2 < 4; ++i2) {
            const int row = rg * 4 + i2;
            const float g = fsigmoid(gacc[i2] + bqv);
            const float cd = ftanh(cacc[i2] + bhv);
            const float h = (1.0f - g) * ph4[i2] + g * cd;
            A2h[(s_h * 64 + q_h * 16 + row) * 8 + j_h] = bf16_rne(h);
        }
    } else {
        // ---- G2: static ksteps s=4..11 concurrent with G1 ----
#pragma unroll
        for (int si = 0; si < 8; ++si) {
            const s16x8 aH = *(const s16x8*)&A2h[((4 + si) * 64 + lane) * 8];
            yacc = __builtin_amdgcn_mfma_f32_16x16x32_bf16(aH, pH[si], yacc, 0, 0, 0);
        }
    }
    __syncthreads();                                        // barrier 2

    // ---- G2: h-dependent ksteps s=0..3 + output ----
    if (role) {
#pragma unroll
        for (int si = 0; si < 4; ++si) {
            const s16x8 aH = *(const s16x8*)&A2h[(si * 64 + lane) * 8];
            yacc = __builtin_amdgcn_mfma_f32_16x16x32_bf16(aH, rH[si], yacc, 0, 0, 0);
        }
        const float bpv = bp[col];
#pragma unroll
        for (int i2 = 0; i2 < 4; ++i2) {
            const int row = rg * 4 + i2;
            out[(row0 + row) * 128 + col] = fsigmoid(yacc[i2] + bpv);
        }
    }
}

extern "C" void kernel_launch(void* const* d_in, const int* in_sizes, int n_in,
                              void* d_out, int out_size, void* d_ws, size_t ws_size,
                              hipStream_t stream) {
    // setup_inputs order:
    // 0:x 1:adj 2:e_t 3:r_t 4:prev_h 5:W_heads 6:a_heads 7:W_out 8:a_out
    // 9:Wq_w 10:Wq_b 11:Wh_w 12:Wh_b 13:Wp_w 14:Wp_b
    const float* x      = (const float*)d_in[0];
    const float* e_t    = (const float*)d_in[2];
    const float* r_t    = (const float*)d_in[3];
    const float* prev_h = (const float*)d_in[4];
    const float* Wq_w   = (const float*)d_in[9];
    const float* Wq_b   = (const float*)d_in[10];
    const float* Wh_w   = (const float*)d_in[11];
    const float* Wh_b   = (const float*)d_in[12];
    const float* Wp_w   = (const float*)d_in[13];
    const float* Wp_b   = (const float*)d_in[14];
    float* out  = (float*)d_out;

    hipLaunchKernelGGL(cekt_fused, dim3(256), dim3(1024), 0, stream,
                       x, e_t, r_t, prev_h, Wq_w, Wh_w, Wp_w,
                       Wq_b, Wh_b, Wp_b, out);
}

// Round 18
// 13.317 us; speedup vs baseline: 1.3138x; 1.3138x over previous
//
#include <hip/hip_runtime.h>
#include <hip/hip_bf16.h>

// CEKT: y_t = sigmoid([h_t|e_t|x] @ Wp + bp)
//   h_t = (1-g)*prev_h + g*tanh(comb @ Wh + bh),  g = sigmoid(comb @ Wq + bq)
//   comb = [e_t | r_t | prev_h];  GAT branch is dead code w.r.t. y_t.
//
// Round-18: r16 (best, 14.59us) + two micro-fixes:
//   (a) native __float2bfloat16 casts (RNE) instead of manual bit-twiddle --
//       lets the compiler emit v_cvt_pk_bf16_f32 (1 instr / 2 elems) for the
//       weight-stream conversion (~1.7us of VALU at 4 ops/elem before).
//   (b) kh0's phase2-remainder B frags issued BEFORE barrier 2 (hq/hc dead
//       there -> no extra register pressure; L2 latency hides under barrier).
// Structure: 256 blocks x 16 rows x 1024 thr (8 col-tiles x 2 k-halves),
// pure bf16 A+W both GEMMs, 3 barriers, fast transcendentals.

typedef short s16x8 __attribute__((ext_vector_type(8)));
typedef float f32x4 __attribute__((ext_vector_type(4)));

constexpr int NKQ = 10;  // K1=320 -> 10 ksteps of 32
constexpr int NKP = 12;  // K2=384 -> 12 ksteps of 32

__device__ __forceinline__ ushort bf16c(float f) {
    __hip_bfloat16 b = __float2bfloat16(f);   // RNE; compiler may use cvt_pk
    return *reinterpret_cast<ushort*>(&b);
}
__device__ __forceinline__ float fsigmoid(float z) {
    return 1.0f / (1.0f + __expf(-z));
}
__device__ __forceinline__ float ftanh(float z) {
    const float a = fabsf(z);
    const float t = __expf(-2.0f * a);
    const float r = (1.0f - t) / (1.0f + t);
    return copysignf(r, z);
}

// Gather one B-fragment (kstep s) from fp32 W, convert to bf16 in registers.
// Elem j: W[s*32 + krow + j][colW] -> 8 dword loads, stride 512B, imm offsets.
__device__ __forceinline__ s16x8 ldfrag(const float* __restrict__ W,
                                        int s, int krow, int colW) {
    const float* p = W + (s * 32 + krow) * 128 + colW;
    float f[8];
#pragma unroll
    for (int j = 0; j < 8; ++j)
        f[j] = p[j * 128];
    union { ushort u[8]; s16x8 v; } r;
#pragma unroll
    for (int j = 0; j < 8; ++j)
        r.u[j] = bf16c(f[j]);
    return r.v;
}

__global__ __launch_bounds__(1024, 1) void cekt_fused(
    const float* __restrict__ x,
    const float* __restrict__ e_t,
    const float* __restrict__ r_t,
    const float* __restrict__ prev_h,
    const float* __restrict__ Wq,
    const float* __restrict__ Wh,
    const float* __restrict__ Wp,
    const float* __restrict__ bq,
    const float* __restrict__ bh,
    const float* __restrict__ bp,
    float* __restrict__ out)
{
    __shared__ alignas(16) ushort A1h[NKQ * 64 * 8];
    __shared__ alignas(16) ushort A2h[NKP * 64 * 8];
    __shared__ f32x4 p1g[8][64], p1c[8][64], p2y[8][64];

    const int t = threadIdx.x;
    const int row0 = blockIdx.x * 16;
    const int w = t >> 6, lane = t & 63;
    const int ct = w & 7, kh = w >> 3;
    const int krow = (lane >> 4) * 8;
    const int colW = ct * 16 + (lane & 15);
    const int colL = lane & 15, rg = lane >> 4;
    const int col = ct * 16 + colL;

    // ---- hoist phase-1 B frags (5 ksteps x {q,c}) ----
    const int sbeg = kh * 5;
    s16x8 hq[5], hc[5];
#pragma unroll
    for (int si = 0; si < 5; ++si) {
        hq[si] = ldfrag(Wq, sbeg + si, krow, colW);
        hc[si] = ldfrag(Wh, sbeg + si, krow, colW);
    }

    // ---- stage A1 (comb1), bf16, coalesced float4 per row ----
    for (int i = t; i < 1280; i += 1024) {
        const int row = i / 80, kq4 = i - row * 80;
        const int k0 = kq4 * 4;
        float4 v;
        if (k0 < 128)      v = *(const float4*)&e_t[(row0 + row) * 128 + k0];
        else if (k0 < 192) v = *(const float4*)&r_t[(row0 + row) * 64 + (k0 - 128)];
        else               v = *(const float4*)&prev_h[(row0 + row) * 128 + (k0 - 192)];
        const int s = k0 >> 5, q = (k0 >> 3) & 3, j0 = k0 & 7;
        const int base = (s * 64 + q * 16 + row) * 8 + j0;
        ushort hi4[4];
        hi4[0] = bf16c(v.x); hi4[1] = bf16c(v.y);
        hi4[2] = bf16c(v.z); hi4[3] = bf16c(v.w);
        *(uint2*)&A1h[base] = *(const uint2*)hi4;
    }
    // ---- stage A2 static part (s=4..11: e_t | x), bf16 ----
    {
        const int row = t >> 6, kr = t & 63;
        const int k0 = 128 + kr * 4;            // 128..380
        const float4 v = (k0 < 256)
            ? *(const float4*)&e_t[(row0 + row) * 128 + (k0 - 128)]
            : *(const float4*)&x[(row0 + row) * 128 + (k0 - 256)];
        const int s = k0 >> 5, q = (k0 >> 3) & 3, j0 = k0 & 7;
        const int base = (s * 64 + q * 16 + row) * 8 + j0;
        ushort hi4[4];
        hi4[0] = bf16c(v.x); hi4[1] = bf16c(v.y);
        hi4[2] = bf16c(v.z); hi4[3] = bf16c(v.w);
        *(uint2*)&A2h[base] = *(const uint2*)hi4;
    }
    __syncthreads();                                        // barrier 1

    // ---- phase 1: g,cand partials, pure bf16 LDS+MFMA (10 MFMA) ----
    f32x4 gacc = {0, 0, 0, 0}, cacc = {0, 0, 0, 0};
#pragma unroll
    for (int si = 0; si < 5; ++si) {
        const int s = sbeg + si;
        const s16x8 aH = *(const s16x8*)&A1h[(s * 64 + lane) * 8];
        gacc = __builtin_amdgcn_mfma_f32_16x16x32_bf16(aH, hq[si], gacc, 0, 0, 0);
        cacc = __builtin_amdgcn_mfma_f32_16x16x32_bf16(aH, hc[si], cacc, 0, 0, 0);
    }

    // kh1: store partials + load phase2-static B (s=6..11).
    // kh0: preload prev_h AND phase2-remainder B (s=0..5) -- hq/hc are dead
    //      here, so no net register growth; latency hides under barrier 2.
    s16x8 pH[6], rH[6];
    float ph4[4];
    if (kh) {
        p1g[ct][lane] = gacc;
        p1c[ct][lane] = cacc;
#pragma unroll
        for (int si = 0; si < 6; ++si)
            pH[si] = ldfrag(Wp, 6 + si, krow, colW);
    } else {
#pragma unroll
        for (int si = 0; si < 6; ++si)
            rH[si] = ldfrag(Wp, si, krow, colW);
#pragma unroll
        for (int i2 = 0; i2 < 4; ++i2)
            ph4[i2] = prev_h[(row0 + rg * 4 + i2) * 128 + col];
    }
    __syncthreads();                                        // barrier 2

    f32x4 yacc = {0, 0, 0, 0};
    if (!kh) {
        // ---- reduce + gate epilogue; h_t written directly in A2-frag layout
        gacc += p1g[ct][lane];
        cacc += p1c[ct][lane];
        const float bqv = bq[col], bhv = bh[col];
        const int s_h = col >> 5, q_h = (col >> 3) & 3, j_h = col & 7;
#pragma unroll
        for (int i2 = 0; i2 < 4; ++i2) {
            const int row = rg * 4 + i2;
            const float g = fsigmoid(gacc[i2] + bqv);
            const float cd = ftanh(cacc[i2] + bhv);
            const float h = (1.0f - g) * ph4[i2] + g * cd;
            A2h[(s_h * 64 + q_h * 16 + row) * 8 + j_h] = bf16c(h);
        }
    } else {
        // ---- phase 2 partials over static ksteps s=6..11 (preloaded B) ----
#pragma unroll
        for (int si = 0; si < 6; ++si) {
            const int s = 6 + si;
            const s16x8 aH = *(const s16x8*)&A2h[(s * 64 + lane) * 8];
            yacc = __builtin_amdgcn_mfma_f32_16x16x32_bf16(aH, pH[si], yacc, 0, 0, 0);
        }
        p2y[ct][lane] = yacc;
    }
    __syncthreads();                                        // barrier 3

    // ---- phase 2 remainder (s=0..5, contains h_t) + output, kh0 waves ----
    if (!kh) {
        yacc = p2y[ct][lane];
#pragma unroll
        for (int si = 0; si < 6; ++si) {
            const s16x8 aH = *(const s16x8*)&A2h[(si * 64 + lane) * 8];
            yacc = __builtin_amdgcn_mfma_f32_16x16x32_bf16(aH, rH[si], yacc, 0, 0, 0);
        }
        const float bpv = bp[col];
#pragma unroll
        for (int i2 = 0; i2 < 4; ++i2) {
            const int row = rg * 4 + i2;
            out[(row0 + row) * 128 + col] = fsigmoid(yacc[i2] + bpv);
        }
    }
}

extern "C" void kernel_launch(void* const* d_in, const int* in_sizes, int n_in,
                              void* d_out, int out_size, void* d_ws, size_t ws_size,
                              hipStream_t stream) {
    // setup_inputs order:
    // 0:x 1:adj 2:e_t 3:r_t 4:prev_h 5:W_heads 6:a_heads 7:W_out 8:a_out
    // 9:Wq_w 10:Wq_b 11:Wh_w 12:Wh_b 13:Wp_w 14:Wp_b
    const float* x      = (const float*)d_in[0];
    const float* e_t    = (const float*)d_in[2];
    const float* r_t    = (const float*)d_in[3];
    const float* prev_h = (const float*)d_in[4];
    const float* Wq_w   = (const float*)d_in[9];
    const float* Wq_b   = (const float*)d_in[10];
    const float* Wh_w   = (const float*)d_in[11];
    const float* Wh_b   = (const float*)d_in[12];
    const float* Wp_w   = (const float*)d_in[13];
    const float* Wp_b   = (const float*)d_in[14];
    float* out  = (float*)d_out;

    hipLaunchKernelGGL(cekt_fused, dim3(256), dim3(1024), 0, stream,
                       x, e_t, r_t, prev_h, Wq_w, Wh_w, Wp_w,
                       Wq_b, Wh_b, Wp_b, out);
}